// Round 22
// baseline (240.605 us; speedup 1.0000x reference)
//
#include <hip/hip_runtime.h>
#include <hip/hip_bf16.h>
#include <math.h>

#define Bc 2
#define Sc 2048
#define Dc 1024
#define Hc 16
#define Ec 64
#define DFFc 4096
#define SCALEc 0.125f
#define SCLOG2E 0.18033688f  /* SCALE * log2(e) */
#define LN_EPSc 1e-5f
#define BH_STRIDE 131072     /* 2048*64 elems per (b,h) slice */

typedef short bf16x8 __attribute__((ext_vector_type(8)));
typedef unsigned short u16x4 __attribute__((ext_vector_type(4)));
typedef unsigned short u16x8 __attribute__((ext_vector_type(8)));
typedef float f32x4 __attribute__((ext_vector_type(4)));
typedef float f32x16 __attribute__((ext_vector_type(16)));
typedef unsigned int u32x4 __attribute__((ext_vector_type(4)));
#define MFMA16(a, b, c) __builtin_amdgcn_mfma_f32_16x16x32_bf16(a, b, c, 0, 0, 0)
#define MFMA32(a, b, c) __builtin_amdgcn_mfma_f32_32x32x16_bf16(a, b, c, 0, 0, 0)
#define GLDS16(g, l)                                                            \
  __builtin_amdgcn_global_load_lds((const __attribute__((address_space(1))) void*)(g), \
                                   (__attribute__((address_space(3))) void*)(l), 16, 0, 0)

static __device__ __forceinline__ unsigned short f2bf(float x) {
  unsigned u = __float_as_uint(x);
  unsigned r = (u + 0x7FFFu + ((u >> 16) & 1u)) >> 16;
  return (unsigned short)r;
}
static __device__ __forceinline__ unsigned cvtpk(float lo, float hi) {
  unsigned r;
  asm("v_cvt_pk_bf16_f32 %0, %1, %2" : "=v"(r) : "v"(lo), "v"(hi));
  return r;
}

// ---------------- prep: weight conversion (6 tensors) + LN1 + qkv-bias concat ------
__global__ __launch_bounds__(256) void prep(
    const float* __restrict__ s3, const float* __restrict__ s4, const float* __restrict__ s5,
    const float* __restrict__ s6, const float* __restrict__ s7, const float* __restrict__ s8,
    unsigned short* __restrict__ wsu,
    const float* __restrict__ x, const float* __restrict__ lw, const float* __restrict__ lb,
    unsigned short* __restrict__ nout,
    const float* __restrict__ qB, const float* __restrict__ kB, const float* __restrict__ vB,
    float* __restrict__ biasF) {
  __shared__ float sm[8];
  int tid = threadIdx.x;
  if (blockIdx.x < 6144) {
    int i = (blockIdx.x * 256 + tid) * 4;
    const float* s;
    int off;
    if (i < 1572864) {         // 3 x 524288: outV, outU, fc1V
      int seg = i >> 19;
      off = i & 524287;
      s = (seg == 0) ? s3 : (seg == 1) ? s4 : s5;
    } else if (i < 3670016) { s = s6; off = i - 1572864; }
    else if (i < 5767168)   { s = s7; off = i - 3670016; }
    else                    { s = s8; off = i - 5767168; }
    float4 v = *(const float4*)(s + off);
    u16x4 o = {f2bf(v.x), f2bf(v.y), f2bf(v.z), f2bf(v.w)};
    *(u16x4*)(wsu + 1572864 + i) = o;
    return;
  }
  if (blockIdx.x >= 6144 + 4096) {
    int k = blockIdx.x - 6144 - 4096;   // 0..2
    const float* src = (k == 0) ? qB : (k == 1) ? kB : vB;
    float sc = (k == 0) ? SCLOG2E : 1.0f;
    int i = tid * 4;
    float4 v = *(const float4*)(src + i);
    float4 o = {v.x * sc, v.y * sc, v.z * sc, v.w * sc};
    *(float4*)(biasF + k * 1024 + i) = o;
    return;
  }
  // LN1 row
  int row = blockIdx.x - 6144;
  const float* xr = x + (size_t)row * Dc;
  float v[4];
  float sum = 0.f;
#pragma unroll
  for (int i = 0; i < 4; ++i) { v[i] = xr[tid + i * 256]; sum += v[i]; }
#pragma unroll
  for (int off = 32; off > 0; off >>= 1) sum += __shfl_down(sum, off, 64);
  if ((tid & 63) == 0) sm[tid >> 6] = sum;
  __syncthreads();
  float mean = (sm[0] + sm[1] + sm[2] + sm[3]) * (1.f / Dc);
  float var = 0.f;
#pragma unroll
  for (int i = 0; i < 4; ++i) { float d0 = v[i] - mean; var += d0 * d0; }
#pragma unroll
  for (int off = 32; off > 0; off >>= 1) var += __shfl_down(var, off, 64);
  if ((tid & 63) == 0) sm[4 + (tid >> 6)] = var;
  __syncthreads();
  float rstd = rsqrtf((sm[4] + sm[5] + sm[6] + sm[7]) * (1.f / Dc) + LN_EPSc);
  unsigned short* orow = nout + (size_t)row * Dc;
#pragma unroll
  for (int i = 0; i < 4; ++i) {
    int c = tid + i * 256;
    orow[c] = f2bf((v[i] - mean) * rstd * lw[c] + lb[c]);
  }
}

// ---------------- transp: out_V fp32 [512,1024] -> bf16 transposed [1024,512] ------
__global__ __launch_bounds__(256) void transp(const float* __restrict__ src,
                                              unsigned short* __restrict__ dst) {
  __shared__ unsigned short T[64][65];
  int bi = blockIdx.x & 15;   // dst-row blocks (1024/64) = src col blocks
  int bj = blockIdx.x >> 4;   // src-row blocks (512/64)
  int tid = threadIdx.x;
  for (int k = 0; k < 16; ++k) {
    int row = (tid >> 6) + k * 4;
    int col = tid & 63;
    T[row][col] = f2bf(src[(size_t)(bj * 64 + row) * 1024 + bi * 64 + col]);
  }
  __syncthreads();
  for (int k = 0; k < 16; ++k) {
    int row = (tid >> 6) + k * 4;
    int col = tid & 63;
    dst[(size_t)(bi * 64 + row) * 512 + bj * 64 + col] = T[col][row];
  }
}

// ---------------- makew: W_qkv[kind*1024 + h*64 + e][d] = sum_r U[h][e][r]*V[h][r][d]
__global__ __launch_bounds__(256) void makew(const float* __restrict__ qU,
                                             const float* __restrict__ kU,
                                             const float* __restrict__ vU,
                                             const float* __restrict__ qV,
                                             const float* __restrict__ kV,
                                             const float* __restrict__ vV,
                                             unsigned short* __restrict__ W) {
  int bid = blockIdx.x;
  int kind = bid >> 8;
  int h = (bid >> 4) & 15;
  int dblk = bid & 15;
  const float* U = (kind == 0) ? qU : (kind == 1) ? kU : vU;
  const float* V = (kind == 0) ? qV : (kind == 1) ? kV : vV;
  __shared__ float Us[64][33];
  __shared__ float Vs[32][64];
  int tid = threadIdx.x;
  for (int i = tid; i < 2048; i += 256) Us[i >> 5][i & 31] = U[h * 2048 + i];
  for (int i = tid; i < 2048; i += 256) {
    int r = i >> 6, d = i & 63;
    Vs[r][d] = V[h * 32768 + r * 1024 + dblk * 64 + d];
  }
  __syncthreads();
  int e = tid & 63;
  int dq = tid >> 6;
  float scale = (kind == 0) ? SCLOG2E : 1.0f;
  float acc[16] = {};
  for (int r = 0; r < 32; ++r) {
    float u = Us[e][r];
#pragma unroll
    for (int j = 0; j < 16; ++j) acc[j] += u * Vs[r][dq * 16 + j];
  }
  u16x8 o0, o1;
#pragma unroll
  for (int j = 0; j < 8; ++j) {
    o0[j] = f2bf(acc[j] * scale);
    o1[j] = f2bf(acc[8 + j] * scale);
  }
  size_t base = ((size_t)(kind * 1024 + h * 64 + e)) * 1024 + dblk * 64 + dq * 16;
  *(u16x8*)(W + base) = o0;
  *(u16x8*)(W + base + 8) = o1;
}

// ---------------- LayerNorm -> bf16 out ----------------
__global__ __launch_bounds__(256) void ln_bf16(const float* __restrict__ x,
                                               const float* __restrict__ w,
                                               const float* __restrict__ b,
                                               unsigned short* __restrict__ out) {
  __shared__ float sm[8];
  int row = blockIdx.x;
  int tid = threadIdx.x;
  const float* xr = x + (size_t)row * Dc;
  float v[4];
  float sum = 0.f;
#pragma unroll
  for (int i = 0; i < 4; ++i) { v[i] = xr[tid + i * 256]; sum += v[i]; }
#pragma unroll
  for (int off = 32; off > 0; off >>= 1) sum += __shfl_down(sum, off, 64);
  if ((tid & 63) == 0) sm[tid >> 6] = sum;
  __syncthreads();
  float mean = (sm[0] + sm[1] + sm[2] + sm[3]) * (1.f / Dc);
  float var = 0.f;
#pragma unroll
  for (int i = 0; i < 4; ++i) { float d0 = v[i] - mean; var += d0 * d0; }
#pragma unroll
  for (int off = 32; off > 0; off >>= 1) var += __shfl_down(var, off, 64);
  if ((tid & 63) == 0) sm[4 + (tid >> 6)] = var;
  __syncthreads();
  float rstd = rsqrtf((sm[4] + sm[5] + sm[6] + sm[7]) * (1.f / Dc) + LN_EPSc);
  unsigned short* orow = out + (size_t)row * Dc;
#pragma unroll
  for (int i = 0; i < 4; ++i) {
    int c = tid + i * 256;
    orow[c] = f2bf((v[i] - mean) * rstd * w[c] + b[c]);
  }
}

// ---------------- bf16 MFMA NT GEMM, double-buffered (r12 proven schedule) ---------
template <int BM, int BN>
__global__ __launch_bounds__(256) void gemm_bf16(const unsigned short* __restrict__ A,
                                                 const unsigned short* __restrict__ W,
                                                 float* __restrict__ Cf,
                                                 unsigned short* __restrict__ Cb,
                                                 const float* __restrict__ bias,
                                                 const float* __restrict__ res,
                                                 int M, int N, int K, int gelu, int nbm) {
  constexpr int BK = 64;
  constexpr int MT = BM / 32;
  constexpr int NT = BN / 32;
  __shared__ unsigned short As[2][BM * BK];
  __shared__ unsigned short Bs[2][BN * BK];
  int tid = threadIdx.x;
  int lane = tid & 63;
  int wid = tid >> 6;
  int cl = lane & 15, grp = lane >> 4;
  int wr = wid >> 1, wc = wid & 1;
  int bm = blockIdx.x % nbm;
  int bn = blockIdx.x / nbm;
  const unsigned short* Ab = A + (size_t)(bm * BM) * K;
  const unsigned short* Wb = W + (size_t)(bn * BN) * K;
  f32x4 acc[MT][NT];
  f32x4 z4 = {0.f, 0.f, 0.f, 0.f};
#pragma unroll
  for (int i = 0; i < MT; ++i)
#pragma unroll
    for (int j = 0; j < NT; ++j) acc[i][j] = z4;
  int r0 = tid >> 3;
  int c0 = (tid & 7) * 8;

#define STAGE(buf, k0)                                                         \
  {                                                                            \
    _Pragma("unroll") for (int l = 0; l < BM / 32; ++l) {                      \
      int row = r0 + l * 32;                                                   \
      int sc = c0 ^ ((row & 7) * 8);                                           \
      GLDS16(Ab + (size_t)row * K + (k0) + sc, &As[buf][(tid + l * 256) * 8]); \
    }                                                                          \
    _Pragma("unroll") for (int l = 0; l < BN / 32; ++l) {                      \
      int row = r0 + l * 32;                                                   \
      int sc = c0 ^ ((row & 7) * 8);                                           \
      GLDS16(Wb + (size_t)row * K + (k0) + sc, &Bs[buf][(tid + l * 256) * 8]); \
    }                                                                          \
  }

  int nt = K / BK;
  STAGE(0, 0)
  __syncthreads();
  for (int t = 0; t < nt; ++t) {
    int cur = t & 1;
    if (t + 1 < nt) STAGE(cur ^ 1, (t + 1) * BK)
#pragma unroll
    for (int kk = 0; kk < 2; ++kk) {
      bf16x8 af[MT], bfr[NT];
#pragma unroll
      for (int i = 0; i < MT; ++i) {
        int row = wr * (BM / 2) + i * 16 + cl;
        af[i] = *(const bf16x8*)&As[cur][row * BK + ((kk * 32 + grp * 8) ^ ((row & 7) * 8))];
      }
#pragma unroll
      for (int j = 0; j < NT; ++j) {
        int row = wc * (BN / 2) + j * 16 + cl;
        bfr[j] = *(const bf16x8*)&Bs[cur][row * BK + ((kk * 32 + grp * 8) ^ ((row & 7) * 8))];
      }
#pragma unroll
      for (int i = 0; i < MT; ++i)
#pragma unroll
        for (int j = 0; j < NT; ++j) acc[i][j] = MFMA16(af[i], bfr[j], acc[i][j]);
    }
    __syncthreads();
  }
#undef STAGE

#pragma unroll
  for (int i = 0; i < MT; ++i) {
    int row = bm * BM + wr * (BM / 2) + i * 16 + grp * 4;
#pragma unroll
    for (int j = 0; j < NT; ++j) {
      int col = bn * BN + wc * (BN / 2) + j * 16 + cl;
      float bv = bias ? bias[col] : 0.f;
#pragma unroll
      for (int r = 0; r < 4; ++r) {
        float v = acc[i][j][r] + bv;
        if (gelu) v = 0.5f * v * (1.f + erff(v * 0.70710678118f));
        if (res) v += res[(size_t)(row + r) * N + col];
        if (Cb) Cb[(size_t)(row + r) * N + col] = f2bf(v);
        else Cf[(size_t)(row + r) * N + col] = v;
      }
    }
  }
}

// ---------------- QKV GEMM (128x64) with fragment-packed epilogue ------------------
__global__ __launch_bounds__(256) void gemm_qkv(const unsigned short* __restrict__ A,
                                                const unsigned short* __restrict__ W,
                                                const float* __restrict__ bias,
                                                unsigned short* __restrict__ qO,
                                                unsigned short* __restrict__ kO,
                                                unsigned short* __restrict__ vO,
                                                int K, int nbm) {
  constexpr int BM = 128, BN = 64, BK = 64;
  constexpr int MT = BM / 32;
  constexpr int NT = BN / 32;
  __shared__ unsigned short As[2][BM * BK];
  __shared__ unsigned short Bs[2][BN * BK];
  int tid = threadIdx.x;
  int lane = tid & 63;
  int wid = tid >> 6;
  int cl = lane & 15, grp = lane >> 4;
  int wr = wid >> 1, wc = wid & 1;
  int bm = blockIdx.x % nbm;
  int bn = blockIdx.x / nbm;
  const unsigned short* Ab = A + (size_t)(bm * BM) * K;
  const unsigned short* Wb = W + (size_t)(bn * BN) * K;
  f32x4 acc[MT][NT];
  f32x4 z4 = {0.f, 0.f, 0.f, 0.f};
#pragma unroll
  for (int i = 0; i < MT; ++i)
#pragma unroll
    for (int j = 0; j < NT; ++j) acc[i][j] = z4;
  int r0 = tid >> 3;
  int c0 = (tid & 7) * 8;

#define STAGE(buf, k0)                                                         \
  {                                                                            \
    _Pragma("unroll") for (int l = 0; l < BM / 32; ++l) {                      \
      int row = r0 + l * 32;                                                   \
      int sc = c0 ^ ((row & 7) * 8);                                           \
      GLDS16(Ab + (size_t)row * K + (k0) + sc, &As[buf][(tid + l * 256) * 8]); \
    }                                                                          \
    _Pragma("unroll") for (int l = 0; l < BN / 32; ++l) {                      \
      int row = r0 + l * 32;                                                   \
      int sc = c0 ^ ((row & 7) * 8);                                           \
      GLDS16(Wb + (size_t)row * K + (k0) + sc, &Bs[buf][(tid + l * 256) * 8]); \
    }                                                                          \
  }

  int nt = K / BK;
  STAGE(0, 0)
  __syncthreads();
  for (int t = 0; t < nt; ++t) {
    int cur = t & 1;
    if (t + 1 < nt) STAGE(cur ^ 1, (t + 1) * BK)
#pragma unroll
    for (int kk = 0; kk < 2; ++kk) {
      bf16x8 af[MT], bfr[NT];
#pragma unroll
      for (int i = 0; i < MT; ++i) {
        int row = wr * (BM / 2) + i * 16 + cl;
        af[i] = *(const bf16x8*)&As[cur][row * BK + ((kk * 32 + grp * 8) ^ ((row & 7) * 8))];
      }
#pragma unroll
      for (int j = 0; j < NT; ++j) {
        int row = wc * (BN / 2) + j * 16 + cl;
        bfr[j] = *(const bf16x8*)&Bs[cur][row * BK + ((kk * 32 + grp * 8) ^ ((row & 7) * 8))];
      }
#pragma unroll
      for (int i = 0; i < MT; ++i)
#pragma unroll
        for (int j = 0; j < NT; ++j) acc[i][j] = MFMA16(af[i], bfr[j], acc[i][j]);
    }
    __syncthreads();
  }
#undef STAGE

#pragma unroll
  for (int i = 0; i < MT; ++i) {
    int row0 = bm * BM + wr * (BM / 2) + i * 16 + grp * 4;
#pragma unroll
    for (int j = 0; j < NT; ++j) {
      int col = bn * BN + wc * (BN / 2) + j * 16 + cl;
      float bv = bias[col];
      int kind = col >> 10;
      int c1 = col & 1023;
      int h = c1 >> 6;
      int e = c1 & 63;
#pragma unroll
      for (int r = 0; r < 4; ++r) {
        int row = row0 + r;
        unsigned short hv = f2bf(acc[i][j][r] + bv);
        int b = row >> 11;
        int rs = row & 2047;
        int sb = rs >> 5;
        int bh = b * Hc + h;
        if (kind < 2) {
          int s = rs & 31;
          int ec = e >> 3;
          int jj = e & 7;
          int es = ec >> 1, hi2 = ec & 1;
          int lanep = s + hi2 * 32;
          unsigned short* out = (kind == 0) ? qO : kO;
          out[(size_t)bh * BH_STRIDE + (size_t)((sb * 4 + es) * 64 + lanep) * 8 + jj] = hv;
        } else {
          int within = rs & 31;
          int sg = within >> 3;
          int si = within & 7;
          int eo = e >> 5, llp = e & 31;
          int h2 = sg >> 1, hi2 = sg & 1;
          int ix = eo * 2 + h2;
          int lanep = llp + hi2 * 32;
          vO[(size_t)bh * BH_STRIDE + (size_t)((sb * 4 + ix) * 64 + lanep) * 8 + si] = hv;
        }
      }
    }
  }
}

// ---------------- Split-K x2 GEMM, fp32 partials into TWO disjoint buffers ---------
template <int BM, int BN>
__global__ __launch_bounds__(256) void gemm_splitk2(const unsigned short* __restrict__ A,
                                                    const unsigned short* __restrict__ W,
                                                    float* __restrict__ P0,
                                                    float* __restrict__ P1,
                                                    int M, int N, int K, int nbm) {
  constexpr int BK = 64;
  constexpr int MT = BM / 32;
  constexpr int NT = BN / 32;
  __shared__ unsigned short As[2][BM * BK];
  __shared__ unsigned short Bs[2][BN * BK];
  int tid = threadIdx.x;
  int lane = tid & 63;
  int wid = tid >> 6;
  int cl = lane & 15, grp = lane >> 4;
  int wr = wid >> 1, wc = wid & 1;
  int per = nbm * (N / BN);
  int slice = blockIdx.x / per;
  int inner = blockIdx.x % per;
  int bm = inner % nbm;
  int bn = inner / nbm;
  int Ks = K / 2;
  const unsigned short* Ab = A + (size_t)(bm * BM) * K + (size_t)slice * Ks;
  const unsigned short* Wb = W + (size_t)(bn * BN) * K + (size_t)slice * Ks;
  float* P = slice ? P1 : P0;
  f32x4 acc[MT][NT];
  f32x4 z4 = {0.f, 0.f, 0.f, 0.f};
#pragma unroll
  for (int i = 0; i < MT; ++i)
#pragma unroll
    for (int j = 0; j < NT; ++j) acc[i][j] = z4;
  int r0 = tid >> 3;
  int c0 = (tid & 7) * 8;

#define STAGE(buf, k0)                                                         \
  {                                                                            \
    _Pragma("unroll") for (int l = 0; l < BM / 32; ++l) {                      \
      int row = r0 + l * 32;                                                   \
      int sc = c0 ^ ((row & 7) * 8);                                           \
      GLDS16(Ab + (size_t)row * K + (k0) + sc, &As[buf][(tid + l * 256) * 8]); \
    }                                                                          \
    _Pragma("unroll") for (int l = 0; l < BN / 32; ++l) {                      \
      int row = r0 + l * 32;                                                   \
      int sc = c0 ^ ((row & 7) * 8);                                           \
      GLDS16(Wb + (size_t)row * K + (k0) + sc, &Bs[buf][(tid + l * 256) * 8]); \
    }                                                                          \
  }

  int nt = Ks / BK;
  STAGE(0, 0)
  __syncthreads();
  for (int t = 0; t < nt; ++t) {
    int cur = t & 1;
    if (t + 1 < nt) STAGE(cur ^ 1, (t + 1) * BK)
#pragma unroll
    for (int kk = 0; kk < 2; ++kk) {
      bf16x8 af[MT], bfr[NT];
#pragma unroll
      for (int i = 0; i < MT; ++i) {
        int row = wr * (BM / 2) + i * 16 + cl;
        af[i] = *(const bf16x8*)&As[cur][row * BK + ((kk * 32 + grp * 8) ^ ((row & 7) * 8))];
      }
#pragma unroll
      for (int j = 0; j < NT; ++j) {
        int row = wc * (BN / 2) + j * 16 + cl;
        bfr[j] = *(const bf16x8*)&Bs[cur][row * BK + ((kk * 32 + grp * 8) ^ ((row & 7) * 8))];
      }
#pragma unroll
      for (int i = 0; i < MT; ++i)
#pragma unroll
        for (int j = 0; j < NT; ++j) acc[i][j] = MFMA16(af[i], bfr[j], acc[i][j]);
    }
    __syncthreads();
  }
#undef STAGE

#pragma unroll
  for (int i = 0; i < MT; ++i) {
    int row = bm * BM + wr * (BM / 2) + i * 16 + grp * 4;
#pragma unroll
    for (int j = 0; j < NT; ++j) {
      int col = bn * BN + wc * (BN / 2) + j * 16 + cl;
#pragma unroll
      for (int r = 0; r < 4; ++r)
        P[(size_t)(row + r) * N + col] = acc[i][j][r];
    }
  }
}

// ---------------- reduce 2 fp32 partials -> bf16 (single rounding) ----------------
__global__ __launch_bounds__(256) void reduce2(const float* __restrict__ P0,
                                               const float* __restrict__ P1,
                                               unsigned short* __restrict__ out, int n) {
  int i = (blockIdx.x * 256 + threadIdx.x) * 4;
  if (i >= n) return;
  float4 a = *(const float4*)(P0 + i);
  float4 b = *(const float4*)(P1 + i);
  u16x4 o = {f2bf(a.x + b.x), f2bf(a.y + b.y), f2bf(a.z + b.z), f2bf(a.w + b.w)};
  *(u16x4*)(out + i) = o;
}

// ---------------- Causal flash attention: swapped-QK^T 32x32 MFMA, NO-MAX softmax --
__global__ __launch_bounds__(256) void attn_mfma(const unsigned short* __restrict__ qf_,
                                                 const unsigned short* __restrict__ kf_,
                                                 const unsigned short* __restrict__ vf_,
                                                 unsigned short* __restrict__ out) {
  __shared__ float MS[2][33][64];
  int tid = threadIdx.x;
  int wid = tid >> 6;
  int lane = tid & 63;
  int ll = lane & 31;
  int hi = lane >> 5;
  int bid = blockIdx.x;
  int xcd = bid & 7;
  int idx = bid >> 3;
  int qt = 63 - (idx >> 2);
  int bh = xcd + 8 * (idx & 3);
  int b = bh >> 4, h = bh & 15;
  const unsigned short* qb = qf_ + (size_t)bh * BH_STRIDE;
  const unsigned short* kb = kf_ + (size_t)bh * BH_STRIDE;
  const unsigned short* vb = vf_ + (size_t)bh * BH_STRIDE;
  int q0 = qt * 32;
  int nt = qt + 1;
  int full = nt - 1;
  int fs = wid * full / 4;
  int fe = (wid + 1) * full / 4;

  bf16x8 qf[4];
#pragma unroll
  for (int es = 0; es < 4; ++es)
    qf[es] = *(const bf16x8*)(qb + (size_t)((qt * 4 + es) * 64 + lane) * 8);

  f32x16 accO[2] = {};
  f32x16 lacc = {};

  int t = fs;
  for (; t + 1 < fe; t += 2) {
    bf16x8 ka[4], kb2[4];
#pragma unroll
    for (int es = 0; es < 4; ++es) {
      ka[es] = *(const bf16x8*)(kb + (size_t)((t * 4 + es) * 64 + lane) * 8);
      kb2[es] = *(const bf16x8*)(kb + (size_t)(((t + 1) * 4 + es) * 64 + lane) * 8);
    }
    f32x16 cA = {}, cB = {};
    __builtin_amdgcn_s_setprio(1);
    cA = MFMA32(ka[0], qf[0], cA);
    cA = MFMA32(ka[1], qf[1], cA);
    cA = MFMA32(ka[2], qf[2], cA);
    cA = MFMA32(ka[3], qf[3], cA);
    cB = MFMA32(kb2[0], qf[0], cB);
    cB = MFMA32(kb2[1], qf[1], cB);
    cB = MFMA32(kb2[2], qf[2], cB);
    cB = MFMA32(kb2[3], qf[3], cB);
    __builtin_amdgcn_s_setprio(0);
    float pA[16], pB[16];
#pragma unroll
    for (int r = 0; r < 16; ++r) { pA[r] = exp2f(cA[r]); pB[r] = exp2f(cB[r]); }
#pragma unroll
    for (int r = 0; r < 16; ++r) lacc[r] += pA[r] + pB[r];
    bf16x8 va[4], vb2[4];
#pragma unroll
    for (int ix = 0; ix < 4; ++ix) {
      va[ix] = *(const bf16x8*)(vb + (size_t)((t * 4 + ix) * 64 + lane) * 8);
      vb2[ix] = *(const bf16x8*)(vb + (size_t)(((t + 1) * 4 + ix) * 64 + lane) * 8);
    }
    unsigned wA0 = cvtpk(pA[0], pA[1]), wA1 = cvtpk(pA[2], pA[3]);
    unsigned wA2 = cvtpk(pA[4], pA[5]), wA3 = cvtpk(pA[6], pA[7]);
    unsigned wA4 = cvtpk(pA[8], pA[9]), wA5 = cvtpk(pA[10], pA[11]);
    unsigned wA6 = cvtpk(pA[12], pA[13]), wA7 = cvtpk(pA[14], pA[15]);
    unsigned wB0 = cvtpk(pB[0], pB[1]), wB1 = cvtpk(pB[2], pB[3]);
    unsigned wB2 = cvtpk(pB[4], pB[5]), wB3 = cvtpk(pB[6], pB[7]);
    unsigned wB4 = cvtpk(pB[8], pB[9]), wB5 = cvtpk(pB[10], pB[11]);
    unsigned wB6 = cvtpk(pB[12], pB[13]), wB7 = cvtpk(pB[14], pB[15]);
    asm("v_permlane32_swap_b32 %0, %1" : "+v"(wA0), "+v"(wA2));
    asm("v_permlane32_swap_b32 %0, %1" : "+v"(wA1), "+v"(wA3));
    asm("v_permlane32_swap_b32 %0, %1" : "+v"(wA4), "+v"(wA6));
    asm("v_permlane32_swap_b32 %0, %1" : "+v"(wA5), "+v"(wA7));
    asm("v_permlane32_swap_b32 %0, %1" : "+v"(wB0), "+v"(wB2));
    asm("v_permlane32_swap_b32 %0, %1" : "+v"(wB1), "+v"(wB3));
    asm("v_permlane32_swap_b32 %0, %1" : "+v"(wB4), "+v"(wB6));
    asm("v_permlane32_swap_b32 %0, %1" : "+v"(wB5), "+v"(wB7));
    u32x4 pA0v = {wA0, wA1, wA2, wA3}, pA1v = {wA4, wA5, wA6, wA7};
    u32x4 pB0v = {wB0, wB1, wB2, wB3}, pB1v = {wB4, wB5, wB6, wB7};
    bf16x8 bA0 = __builtin_bit_cast(bf16x8, pA0v), bA1 = __builtin_bit_cast(bf16x8, pA1v);
    bf16x8 bB0 = __builtin_bit_cast(bf16x8, pB0v), bB1 = __builtin_bit_cast(bf16x8, pB1v);
    __builtin_amdgcn_s_setprio(1);
    accO[0] = MFMA32(va[0], bA0, accO[0]);
    accO[0] = MFMA32(va[1], bA1, accO[0]);
    accO[0] = MFMA32(vb2[0], bB0, accO[0]);
    accO[0] = MFMA32(vb2[1], bB1, accO[0]);
    accO[1] = MFMA32(va[2], bA0, accO[1]);
    accO[1] = MFMA32(va[3], bA1, accO[1]);
    accO[1] = MFMA32(vb2[2], bB0, accO[1]);
    accO[1] = MFMA32(vb2[3], bB1, accO[1]);
    __builtin_amdgcn_s_setprio(0);
  }

#define ATT_ONE(T, MASKED)                                                          \
  {                                                                                 \
    bf16x8 kf1[4];                                                                  \
    _Pragma("unroll") for (int es = 0; es < 4; ++es)                                \
      kf1[es] = *(const bf16x8*)(kb + (size_t)(((T) * 4 + es) * 64 + lane) * 8);    \
    f32x16 c = {};                                                                  \
    __builtin_amdgcn_s_setprio(1);                                                  \
    c = MFMA32(kf1[0], qf[0], c);                                                   \
    c = MFMA32(kf1[1], qf[1], c);                                                   \
    c = MFMA32(kf1[2], qf[2], c);                                                   \
    c = MFMA32(kf1[3], qf[3], c);                                                   \
    __builtin_amdgcn_s_setprio(0);                                                  \
    float p1[16];                                                                   \
    _Pragma("unroll") for (int r = 0; r < 16; ++r) {                                \
      if (MASKED) {                                                                 \
        int keyloc = (r & 3) + 8 * (r >> 2) + 4 * hi;                               \
        p1[r] = (keyloc > ll) ? 0.f : exp2f(c[r]);                                  \
      } else p1[r] = exp2f(c[r]);                                                   \
    }                                                                               \
    _Pragma("unroll") for (int r = 0; r < 16; ++r) lacc[r] += p1[r];                \
    bf16x8 vf1[4];                                                                  \
    _Pragma("unroll") for (int ix = 0; ix < 4; ++ix)                                \
      vf1[ix] = *(const bf16x8*)(vb + (size_t)(((T) * 4 + ix) * 64 + lane) * 8);    \
    unsigned w0 = cvtpk(p1[0], p1[1]), w1 = cvtpk(p1[2], p1[3]);                    \
    unsigned w2 = cvtpk(p1[4], p1[5]), w3 = cvtpk(p1[6], p1[7]);                    \
    unsigned w4 = cvtpk(p1[8], p1[9]), w5 = cvtpk(p1[10], p1[11]);                  \
    unsigned w6 = cvtpk(p1[12], p1[13]), w7 = cvtpk(p1[14], p1[15]);                \
    asm("v_permlane32_swap_b32 %0, %1" : "+v"(w0), "+v"(w2));                       \
    asm("v_permlane32_swap_b32 %0, %1" : "+v"(w1), "+v"(w3));                       \
    asm("v_permlane32_swap_b32 %0, %1" : "+v"(w4), "+v"(w6));                       \
    asm("v_permlane32_swap_b32 %0, %1" : "+v"(w5), "+v"(w7));                       \
    u32x4 pw0 = {w0, w1, w2, w3};                                                   \
    u32x4 pw1 = {w4, w5, w6, w7};                                                   \
    bf16x8 pb0 = __builtin_bit_cast(bf16x8, pw0);                                   \
    bf16x8 pb1 = __builtin_bit_cast(bf16x8, pw1);                                   \
    __builtin_amdgcn_s_setprio(1);                                                  \
    accO[0] = MFMA32(vf1[0], pb0, accO[0]);                                         \
    accO[0] = MFMA32(vf1[1], pb1, accO[0]);                                         \
    accO[1] = MFMA32(vf1[2], pb0, accO[1]);                                         \
    accO[1] = MFMA32(vf1[3], pb1, accO[1]);                                         \
    __builtin_amdgcn_s_setprio(0);                                                  \
  }

  if (t < fe) ATT_ONE(t, false)
  if (wid == 3) ATT_ONE(full, true)
#undef ATT_ONE

  float l;
  {
    float s8[8];
#pragma unroll
    for (int r = 0; r < 8; ++r) s8[r] = lacc[r] + lacc[r + 8];
    float s4a = s8[0] + s8[4], s4b = s8[1] + s8[5], s4c = s8[2] + s8[6], s4d = s8[3] + s8[7];
    l = (s4a + s4b) + (s4c + s4d);
  }

  auto publish = [&](int slot) {
#pragma unroll
    for (int r = 0; r < 16; ++r) {
      MS[slot][r][lane] = accO[0][r];
      MS[slot][16 + r][lane] = accO[1][r];
    }
    MS[slot][32][lane] = l;
  };
  auto merge = [&](int slot) {
    l += MS[slot][32][lane];
#pragma unroll
    for (int r = 0; r < 16; ++r) {
      accO[0][r] += MS[slot][r][lane];
      accO[1][r] += MS[slot][16 + r][lane];
    }
  };
  if (wid == 1) publish(0);
  if (wid == 3) publish(1);
  __syncthreads();
  if (wid == 0) merge(0);
  if (wid == 2) merge(1);
  __syncthreads();
  if (wid == 2) publish(0);
  __syncthreads();
  if (wid == 0) {
    merge(0);
    float ltot = l + __shfl_xor(l, 32, 64);
    float inv = 1.f / ltot;
    unsigned short* orow = out + (size_t)(b * Sc + q0 + ll) * Dc + h * Ec;
#pragma unroll
    for (int eo = 0; eo < 2; ++eo)
#pragma unroll
      for (int g = 0; g < 4; ++g) {
        u16x4 o4 = {f2bf(accO[eo][4 * g + 0] * inv), f2bf(accO[eo][4 * g + 1] * inv),
                    f2bf(accO[eo][4 * g + 2] * inv), f2bf(accO[eo][4 * g + 3] * inv)};
        *(u16x4*)(orow + eo * 32 + 8 * g + 4 * hi) = o4;
      }
  }
}

extern "C" void kernel_launch(void* const* d_in, const int* in_sizes, int n_in,
                              void* d_out, int out_size, void* d_ws, size_t ws_size,
                              hipStream_t stream) {
  const float* hidden = (const float*)d_in[0];
  const float* ln1_w = (const float*)d_in[1];
  const float* ln1_b = (const float*)d_in[2];
  const float* q_U = (const float*)d_in[3];
  const float* q_V = (const float*)d_in[4];
  const float* q_bias = (const float*)d_in[5];
  const float* k_U = (const float*)d_in[6];
  const float* k_V = (const float*)d_in[7];
  const float* k_bias = (const float*)d_in[8];
  const float* v_U = (const float*)d_in[9];
  const float* v_V = (const float*)d_in[10];
  const float* v_bias = (const float*)d_in[11];
  const float* out_U = (const float*)d_in[12];
  const float* out_V = (const float*)d_in[13];
  const float* out_bias = (const float*)d_in[14];
  const float* ln2_w = (const float*)d_in[15];
  const float* ln2_b = (const float*)d_in[16];
  const float* fc1_U = (const float*)d_in[17];
  const float* fc1_V = (const float*)d_in[18];
  const float* fc1_bias = (const float*)d_in[19];
  const float* fc2_U = (const float*)d_in[20];
  const float* fc2_V = (const float*)d_in[21];
  const float* fc2_bias = (const float*)d_in[22];
  float* out = (float*)d_out;
  float* ws = (float*)d_ws;
  unsigned short* wsu = (unsigned short*)d_ws;

  // ---- bf16 weight arena (ushort offsets) ----
  // dead wQKV slot [0,1572864) now hosts: WOUT [1024,1024] at 0 (1,048,576 u16)
  //                                       wOUTVT [1024,512] at 1048576 (524,288 u16)
  unsigned short* WOUT = wsu;
  unsigned short* wOUTVT = wsu + 1048576;
  unsigned short* wOUTV = wsu + 1572864;    // [512,1024] (converted; unused now)
  unsigned short* wOUTU = wsu + 2097152;    // [1024,512]
  unsigned short* wFC1V = wsu + 2621440;    // [512,1024]
  unsigned short* wFC1U = wsu + 3145728;    // [4096,512]
  unsigned short* wFC2V = wsu + 5242880;    // [512,4096]
  unsigned short* wFC2U = wsu + 7340032;    // [1024,512]

  // ---- activation arena (float offsets) — identical to r21 (audited) ----
  float* h1 = ws + 4194304;
  unsigned short* Wqkv = (unsigned short*)(ws + 4194304);      // [3072,1024] bf16 (dead h1)
  float* qkv_biasF = ws + 6000000;                             // [3072] fp32 (dead h1)
  unsigned short* attn_out = (unsigned short*)(ws + 6291456);
  unsigned short* normed = (unsigned short*)(ws + 8388608);
  unsigned short* rbB = (unsigned short*)(ws + 10485760);
  unsigned short* ff = (unsigned short*)(ws + 11534336);
  unsigned short* qbuf = (unsigned short*)(ws + 16777216);
  unsigned short* kbuf = (unsigned short*)(ws + 18874368);
  unsigned short* vtbuf = (unsigned short*)(ws + 20971520);
  float* P0f = ws + 8388608;                                   // (dead normed)
  float* P1f = ws + 19922944;                                  // (dead vt region)
  unsigned short* rbG2 = (unsigned short*)(ws + 10485760);     // (dead rbB)

  const int M = Bc * Sc;  // 4096
  dim3 blk(256);

  // ---- out_V^T (bf16) from fp32 source; independent of prep ----
  transp<<<128, blk, 0, stream>>>(out_V, wOUTVT);
  // ---- W_qkv = U·V per head (+SCLOG2E fold on q) ----
  makew<<<768, blk, 0, stream>>>(q_U, k_U, v_U, q_V, k_V, v_V, Wqkv);
  // ---- weight conversion + LN1 + qkv-bias concat ----
  prep<<<6144 + M + 3, blk, 0, stream>>>(out_V, out_U, fc1_V, fc1_U, fc2_V, fc2_U,
                                         wsu, hidden, ln1_w, ln1_b, normed,
                                         q_bias, k_bias, v_bias, qkv_biasF);
  // ---- W_out = out_U · out_V (dense [1024,1024], bf16) ----
  gemm_bf16<64, 64><<<256, blk, 0, stream>>>(wOUTU, wOUTVT, nullptr, WOUT, nullptr, nullptr,
                                             1024, 1024, 512, 0, 16);

  // ---- fused dense QKV projection, writes fragment-packed q/k/vt directly ----
  gemm_qkv<<<1536, blk, 0, stream>>>(normed, Wqkv, qkv_biasF, qbuf, kbuf, vtbuf, Dc, 32);

  // ---- causal attention -> attn_out (bf16) ----
  attn_mfma<<<2048, blk, 0, stream>>>(qbuf, kbuf, vtbuf, attn_out);

  // ---- output projection (single dense GEMM) + residual -> h1 (fp32) ----
  gemm_bf16<128, 64><<<512, blk, 0, stream>>>(attn_out, WOUT, h1, nullptr, out_bias, hidden,
                                              M, Dc, Dc, 0, 32);

  // ---- LN2 + FF ----
  ln_bf16<<<M, blk, 0, stream>>>(h1, ln2_w, ln2_b, normed);
  gemm_bf16<64, 32><<<1024, blk, 0, stream>>>(normed, wFC1V, nullptr, rbB, nullptr, nullptr,
                                              M, 512, Dc, 0, 64);
  gemm_bf16<128, 64><<<2048, blk, 0, stream>>>(rbB, wFC1U, nullptr, ff, fc1_bias, nullptr,
                                               M, DFFc, 512, 1, 32);
  // ---- fc2_V split-K x2 (fp32 partials, disjoint buffers, exact reduce) ----
  gemm_splitk2<64, 64><<<1024, blk, 0, stream>>>(ff, wFC2V, P0f, P1f, M, 512, DFFc, 64);
  reduce2<<<2048, blk, 0, stream>>>(P0f, P1f, rbG2, M * 512);
  gemm_bf16<64, 64><<<1024, blk, 0, stream>>>(rbG2, wFC2U, out, nullptr, fc2_bias, h1,
                                              M, Dc, 512, 0, 64);
}

// Round 23
// 229.726 us; speedup vs baseline: 1.0474x; 1.0474x over previous
//
#include <hip/hip_runtime.h>
#include <hip/hip_bf16.h>
#include <math.h>

#define Bc 2
#define Sc 2048
#define Dc 1024
#define Hc 16
#define Ec 64
#define DFFc 4096
#define SCALEc 0.125f
#define SCLOG2E 0.18033688f  /* SCALE * log2(e) */
#define LN_EPSc 1e-5f
#define BH_STRIDE 131072     /* 2048*64 elems per (b,h) slice */

typedef short bf16x8 __attribute__((ext_vector_type(8)));
typedef unsigned short u16x4 __attribute__((ext_vector_type(4)));
typedef unsigned short u16x8 __attribute__((ext_vector_type(8)));
typedef float f32x4 __attribute__((ext_vector_type(4)));
typedef float f32x16 __attribute__((ext_vector_type(16)));
typedef unsigned int u32x4 __attribute__((ext_vector_type(4)));
#define MFMA16(a, b, c) __builtin_amdgcn_mfma_f32_16x16x32_bf16(a, b, c, 0, 0, 0)
#define MFMA32(a, b, c) __builtin_amdgcn_mfma_f32_32x32x16_bf16(a, b, c, 0, 0, 0)
#define GLDS16(g, l)                                                            \
  __builtin_amdgcn_global_load_lds((const __attribute__((address_space(1))) void*)(g), \
                                   (__attribute__((address_space(3))) void*)(l), 16, 0, 0)

static __device__ __forceinline__ unsigned short f2bf(float x) {
  unsigned u = __float_as_uint(x);
  unsigned r = (u + 0x7FFFu + ((u >> 16) & 1u)) >> 16;
  return (unsigned short)r;
}
static __device__ __forceinline__ unsigned cvtpk(float lo, float hi) {
  unsigned r;
  asm("v_cvt_pk_bf16_f32 %0, %1, %2" : "=v"(r) : "v"(lo), "v"(hi));
  return r;
}

// ---------------- prep: weight conversion (6 tensors) + LN1 + qkv-bias concat ------
__global__ __launch_bounds__(256) void prep(
    const float* __restrict__ s3, const float* __restrict__ s4, const float* __restrict__ s5,
    const float* __restrict__ s6, const float* __restrict__ s7, const float* __restrict__ s8,
    unsigned short* __restrict__ wsu,
    const float* __restrict__ x, const float* __restrict__ lw, const float* __restrict__ lb,
    unsigned short* __restrict__ nout,
    const float* __restrict__ qB, const float* __restrict__ kB, const float* __restrict__ vB,
    float* __restrict__ biasF) {
  __shared__ float sm[8];
  int tid = threadIdx.x;
  if (blockIdx.x < 6144) {
    int i = (blockIdx.x * 256 + tid) * 4;
    const float* s;
    int off;
    if (i < 1572864) {         // 3 x 524288: outV, outU, fc1V
      int seg = i >> 19;
      off = i & 524287;
      s = (seg == 0) ? s3 : (seg == 1) ? s4 : s5;
    } else if (i < 3670016) { s = s6; off = i - 1572864; }
    else if (i < 5767168)   { s = s7; off = i - 3670016; }
    else                    { s = s8; off = i - 5767168; }
    float4 v = *(const float4*)(s + off);
    u16x4 o = {f2bf(v.x), f2bf(v.y), f2bf(v.z), f2bf(v.w)};
    *(u16x4*)(wsu + 1572864 + i) = o;
    return;
  }
  if (blockIdx.x >= 6144 + 4096) {
    int k = blockIdx.x - 6144 - 4096;   // 0..2
    const float* src = (k == 0) ? qB : (k == 1) ? kB : vB;
    float sc = (k == 0) ? SCLOG2E : 1.0f;
    int i = tid * 4;
    float4 v = *(const float4*)(src + i);
    float4 o = {v.x * sc, v.y * sc, v.z * sc, v.w * sc};
    *(float4*)(biasF + k * 1024 + i) = o;
    return;
  }
  // LN1 row
  int row = blockIdx.x - 6144;
  const float* xr = x + (size_t)row * Dc;
  float v[4];
  float sum = 0.f;
#pragma unroll
  for (int i = 0; i < 4; ++i) { v[i] = xr[tid + i * 256]; sum += v[i]; }
#pragma unroll
  for (int off = 32; off > 0; off >>= 1) sum += __shfl_down(sum, off, 64);
  if ((tid & 63) == 0) sm[tid >> 6] = sum;
  __syncthreads();
  float mean = (sm[0] + sm[1] + sm[2] + sm[3]) * (1.f / Dc);
  float var = 0.f;
#pragma unroll
  for (int i = 0; i < 4; ++i) { float d0 = v[i] - mean; var += d0 * d0; }
#pragma unroll
  for (int off = 32; off > 0; off >>= 1) var += __shfl_down(var, off, 64);
  if ((tid & 63) == 0) sm[4 + (tid >> 6)] = var;
  __syncthreads();
  float rstd = rsqrtf((sm[4] + sm[5] + sm[6] + sm[7]) * (1.f / Dc) + LN_EPSc);
  unsigned short* orow = nout + (size_t)row * Dc;
#pragma unroll
  for (int i = 0; i < 4; ++i) {
    int c = tid + i * 256;
    orow[c] = f2bf((v[i] - mean) * rstd * lw[c] + lb[c]);
  }
}

// ---------------- makew: W_qkv[kind*1024 + h*64 + e][d] = sum_r U[h][e][r]*V[h][r][d]
__global__ __launch_bounds__(256) void makew(const float* __restrict__ qU,
                                             const float* __restrict__ kU,
                                             const float* __restrict__ vU,
                                             const float* __restrict__ qV,
                                             const float* __restrict__ kV,
                                             const float* __restrict__ vV,
                                             unsigned short* __restrict__ W) {
  int bid = blockIdx.x;
  int kind = bid >> 8;
  int h = (bid >> 4) & 15;
  int dblk = bid & 15;
  const float* U = (kind == 0) ? qU : (kind == 1) ? kU : vU;
  const float* V = (kind == 0) ? qV : (kind == 1) ? kV : vV;
  __shared__ float Us[64][33];
  __shared__ float Vs[32][64];
  int tid = threadIdx.x;
  for (int i = tid; i < 2048; i += 256) Us[i >> 5][i & 31] = U[h * 2048 + i];
  for (int i = tid; i < 2048; i += 256) {
    int r = i >> 6, d = i & 63;
    Vs[r][d] = V[h * 32768 + r * 1024 + dblk * 64 + d];
  }
  __syncthreads();
  int e = tid & 63;
  int dq = tid >> 6;
  float scale = (kind == 0) ? SCLOG2E : 1.0f;
  float acc[16] = {};
  for (int r = 0; r < 32; ++r) {
    float u = Us[e][r];
#pragma unroll
    for (int j = 0; j < 16; ++j) acc[j] += u * Vs[r][dq * 16 + j];
  }
  u16x8 o0, o1;
#pragma unroll
  for (int j = 0; j < 8; ++j) {
    o0[j] = f2bf(acc[j] * scale);
    o1[j] = f2bf(acc[8 + j] * scale);
  }
  size_t base = ((size_t)(kind * 1024 + h * 64 + e)) * 1024 + dblk * 64 + dq * 16;
  *(u16x8*)(W + base) = o0;
  *(u16x8*)(W + base + 8) = o1;
}

// ---------------- LayerNorm -> bf16 out ----------------
__global__ __launch_bounds__(256) void ln_bf16(const float* __restrict__ x,
                                               const float* __restrict__ w,
                                               const float* __restrict__ b,
                                               unsigned short* __restrict__ out) {
  __shared__ float sm[8];
  int row = blockIdx.x;
  int tid = threadIdx.x;
  const float* xr = x + (size_t)row * Dc;
  float v[4];
  float sum = 0.f;
#pragma unroll
  for (int i = 0; i < 4; ++i) { v[i] = xr[tid + i * 256]; sum += v[i]; }
#pragma unroll
  for (int off = 32; off > 0; off >>= 1) sum += __shfl_down(sum, off, 64);
  if ((tid & 63) == 0) sm[tid >> 6] = sum;
  __syncthreads();
  float mean = (sm[0] + sm[1] + sm[2] + sm[3]) * (1.f / Dc);
  float var = 0.f;
#pragma unroll
  for (int i = 0; i < 4; ++i) { float d0 = v[i] - mean; var += d0 * d0; }
#pragma unroll
  for (int off = 32; off > 0; off >>= 1) var += __shfl_down(var, off, 64);
  if ((tid & 63) == 0) sm[4 + (tid >> 6)] = var;
  __syncthreads();
  float rstd = rsqrtf((sm[4] + sm[5] + sm[6] + sm[7]) * (1.f / Dc) + LN_EPSc);
  unsigned short* orow = out + (size_t)row * Dc;
#pragma unroll
  for (int i = 0; i < 4; ++i) {
    int c = tid + i * 256;
    orow[c] = f2bf((v[i] - mean) * rstd * w[c] + b[c]);
  }
}

// ---------------- bf16 MFMA NT GEMM, double-buffered (r12 proven schedule) ---------
template <int BM, int BN>
__global__ __launch_bounds__(256) void gemm_bf16(const unsigned short* __restrict__ A,
                                                 const unsigned short* __restrict__ W,
                                                 float* __restrict__ Cf,
                                                 unsigned short* __restrict__ Cb,
                                                 const float* __restrict__ bias,
                                                 const float* __restrict__ res,
                                                 int M, int N, int K, int gelu, int nbm) {
  constexpr int BK = 64;
  constexpr int MT = BM / 32;
  constexpr int NT = BN / 32;
  __shared__ unsigned short As[2][BM * BK];
  __shared__ unsigned short Bs[2][BN * BK];
  int tid = threadIdx.x;
  int lane = tid & 63;
  int wid = tid >> 6;
  int cl = lane & 15, grp = lane >> 4;
  int wr = wid >> 1, wc = wid & 1;
  int bm = blockIdx.x % nbm;
  int bn = blockIdx.x / nbm;
  const unsigned short* Ab = A + (size_t)(bm * BM) * K;
  const unsigned short* Wb = W + (size_t)(bn * BN) * K;
  f32x4 acc[MT][NT];
  f32x4 z4 = {0.f, 0.f, 0.f, 0.f};
#pragma unroll
  for (int i = 0; i < MT; ++i)
#pragma unroll
    for (int j = 0; j < NT; ++j) acc[i][j] = z4;
  int r0 = tid >> 3;
  int c0 = (tid & 7) * 8;

#define STAGE(buf, k0)                                                         \
  {                                                                            \
    _Pragma("unroll") for (int l = 0; l < BM / 32; ++l) {                      \
      int row = r0 + l * 32;                                                   \
      int sc = c0 ^ ((row & 7) * 8);                                           \
      GLDS16(Ab + (size_t)row * K + (k0) + sc, &As[buf][(tid + l * 256) * 8]); \
    }                                                                          \
    _Pragma("unroll") for (int l = 0; l < BN / 32; ++l) {                      \
      int row = r0 + l * 32;                                                   \
      int sc = c0 ^ ((row & 7) * 8);                                           \
      GLDS16(Wb + (size_t)row * K + (k0) + sc, &Bs[buf][(tid + l * 256) * 8]); \
    }                                                                          \
  }

  int nt = K / BK;
  STAGE(0, 0)
  __syncthreads();
  for (int t = 0; t < nt; ++t) {
    int cur = t & 1;
    if (t + 1 < nt) STAGE(cur ^ 1, (t + 1) * BK)
#pragma unroll
    for (int kk = 0; kk < 2; ++kk) {
      bf16x8 af[MT], bfr[NT];
#pragma unroll
      for (int i = 0; i < MT; ++i) {
        int row = wr * (BM / 2) + i * 16 + cl;
        af[i] = *(const bf16x8*)&As[cur][row * BK + ((kk * 32 + grp * 8) ^ ((row & 7) * 8))];
      }
#pragma unroll
      for (int j = 0; j < NT; ++j) {
        int row = wc * (BN / 2) + j * 16 + cl;
        bfr[j] = *(const bf16x8*)&Bs[cur][row * BK + ((kk * 32 + grp * 8) ^ ((row & 7) * 8))];
      }
#pragma unroll
      for (int i = 0; i < MT; ++i)
#pragma unroll
        for (int j = 0; j < NT; ++j) acc[i][j] = MFMA16(af[i], bfr[j], acc[i][j]);
    }
    __syncthreads();
  }
#undef STAGE

#pragma unroll
  for (int i = 0; i < MT; ++i) {
    int row = bm * BM + wr * (BM / 2) + i * 16 + grp * 4;
#pragma unroll
    for (int j = 0; j < NT; ++j) {
      int col = bn * BN + wc * (BN / 2) + j * 16 + cl;
      float bv = bias ? bias[col] : 0.f;
#pragma unroll
      for (int r = 0; r < 4; ++r) {
        float v = acc[i][j][r] + bv;
        if (gelu) v = 0.5f * v * (1.f + erff(v * 0.70710678118f));
        if (res) v += res[(size_t)(row + r) * N + col];
        if (Cb) Cb[(size_t)(row + r) * N + col] = f2bf(v);
        else Cf[(size_t)(row + r) * N + col] = v;
      }
    }
  }
}

// ---------------- QKV GEMM (128x64) with fragment-packed epilogue ------------------
__global__ __launch_bounds__(256) void gemm_qkv(const unsigned short* __restrict__ A,
                                                const unsigned short* __restrict__ W,
                                                const float* __restrict__ bias,
                                                unsigned short* __restrict__ qO,
                                                unsigned short* __restrict__ kO,
                                                unsigned short* __restrict__ vO,
                                                int K, int nbm) {
  constexpr int BM = 128, BN = 64, BK = 64;
  constexpr int MT = BM / 32;
  constexpr int NT = BN / 32;
  __shared__ unsigned short As[2][BM * BK];
  __shared__ unsigned short Bs[2][BN * BK];
  int tid = threadIdx.x;
  int lane = tid & 63;
  int wid = tid >> 6;
  int cl = lane & 15, grp = lane >> 4;
  int wr = wid >> 1, wc = wid & 1;
  int bm = blockIdx.x % nbm;
  int bn = blockIdx.x / nbm;
  const unsigned short* Ab = A + (size_t)(bm * BM) * K;
  const unsigned short* Wb = W + (size_t)(bn * BN) * K;
  f32x4 acc[MT][NT];
  f32x4 z4 = {0.f, 0.f, 0.f, 0.f};
#pragma unroll
  for (int i = 0; i < MT; ++i)
#pragma unroll
    for (int j = 0; j < NT; ++j) acc[i][j] = z4;
  int r0 = tid >> 3;
  int c0 = (tid & 7) * 8;

#define STAGE(buf, k0)                                                         \
  {                                                                            \
    _Pragma("unroll") for (int l = 0; l < BM / 32; ++l) {                      \
      int row = r0 + l * 32;                                                   \
      int sc = c0 ^ ((row & 7) * 8);                                           \
      GLDS16(Ab + (size_t)row * K + (k0) + sc, &As[buf][(tid + l * 256) * 8]); \
    }                                                                          \
    _Pragma("unroll") for (int l = 0; l < BN / 32; ++l) {                      \
      int row = r0 + l * 32;                                                   \
      int sc = c0 ^ ((row & 7) * 8);                                           \
      GLDS16(Wb + (size_t)row * K + (k0) + sc, &Bs[buf][(tid + l * 256) * 8]); \
    }                                                                          \
  }

  int nt = K / BK;
  STAGE(0, 0)
  __syncthreads();
  for (int t = 0; t < nt; ++t) {
    int cur = t & 1;
    if (t + 1 < nt) STAGE(cur ^ 1, (t + 1) * BK)
#pragma unroll
    for (int kk = 0; kk < 2; ++kk) {
      bf16x8 af[MT], bfr[NT];
#pragma unroll
      for (int i = 0; i < MT; ++i) {
        int row = wr * (BM / 2) + i * 16 + cl;
        af[i] = *(const bf16x8*)&As[cur][row * BK + ((kk * 32 + grp * 8) ^ ((row & 7) * 8))];
      }
#pragma unroll
      for (int j = 0; j < NT; ++j) {
        int row = wc * (BN / 2) + j * 16 + cl;
        bfr[j] = *(const bf16x8*)&Bs[cur][row * BK + ((kk * 32 + grp * 8) ^ ((row & 7) * 8))];
      }
#pragma unroll
      for (int i = 0; i < MT; ++i)
#pragma unroll
        for (int j = 0; j < NT; ++j) acc[i][j] = MFMA16(af[i], bfr[j], acc[i][j]);
    }
    __syncthreads();
  }
#undef STAGE

#pragma unroll
  for (int i = 0; i < MT; ++i) {
    int row0 = bm * BM + wr * (BM / 2) + i * 16 + grp * 4;
#pragma unroll
    for (int j = 0; j < NT; ++j) {
      int col = bn * BN + wc * (BN / 2) + j * 16 + cl;
      float bv = bias[col];
      int kind = col >> 10;
      int c1 = col & 1023;
      int h = c1 >> 6;
      int e = c1 & 63;
#pragma unroll
      for (int r = 0; r < 4; ++r) {
        int row = row0 + r;
        unsigned short hv = f2bf(acc[i][j][r] + bv);
        int b = row >> 11;
        int rs = row & 2047;
        int sb = rs >> 5;
        int bh = b * Hc + h;
        if (kind < 2) {
          int s = rs & 31;
          int ec = e >> 3;
          int jj = e & 7;
          int es = ec >> 1, hi2 = ec & 1;
          int lanep = s + hi2 * 32;
          unsigned short* out = (kind == 0) ? qO : kO;
          out[(size_t)bh * BH_STRIDE + (size_t)((sb * 4 + es) * 64 + lanep) * 8 + jj] = hv;
        } else {
          int within = rs & 31;
          int sg = within >> 3;
          int si = within & 7;
          int eo = e >> 5, llp = e & 31;
          int h2 = sg >> 1, hi2 = sg & 1;
          int ix = eo * 2 + h2;
          int lanep = llp + hi2 * 32;
          vO[(size_t)bh * BH_STRIDE + (size_t)((sb * 4 + ix) * 64 + lanep) * 8 + si] = hv;
        }
      }
    }
  }
}

// ---------------- Split-K x2 GEMM, fp32 partials into TWO disjoint buffers ---------
template <int BM, int BN>
__global__ __launch_bounds__(256) void gemm_splitk2(const unsigned short* __restrict__ A,
                                                    const unsigned short* __restrict__ W,
                                                    float* __restrict__ P0,
                                                    float* __restrict__ P1,
                                                    int M, int N, int K, int nbm) {
  constexpr int BK = 64;
  constexpr int MT = BM / 32;
  constexpr int NT = BN / 32;
  __shared__ unsigned short As[2][BM * BK];
  __shared__ unsigned short Bs[2][BN * BK];
  int tid = threadIdx.x;
  int lane = tid & 63;
  int wid = tid >> 6;
  int cl = lane & 15, grp = lane >> 4;
  int wr = wid >> 1, wc = wid & 1;
  int per = nbm * (N / BN);
  int slice = blockIdx.x / per;
  int inner = blockIdx.x % per;
  int bm = inner % nbm;
  int bn = inner / nbm;
  int Ks = K / 2;
  const unsigned short* Ab = A + (size_t)(bm * BM) * K + (size_t)slice * Ks;
  const unsigned short* Wb = W + (size_t)(bn * BN) * K + (size_t)slice * Ks;
  float* P = slice ? P1 : P0;
  f32x4 acc[MT][NT];
  f32x4 z4 = {0.f, 0.f, 0.f, 0.f};
#pragma unroll
  for (int i = 0; i < MT; ++i)
#pragma unroll
    for (int j = 0; j < NT; ++j) acc[i][j] = z4;
  int r0 = tid >> 3;
  int c0 = (tid & 7) * 8;

#define STAGE(buf, k0)                                                         \
  {                                                                            \
    _Pragma("unroll") for (int l = 0; l < BM / 32; ++l) {                      \
      int row = r0 + l * 32;                                                   \
      int sc = c0 ^ ((row & 7) * 8);                                           \
      GLDS16(Ab + (size_t)row * K + (k0) + sc, &As[buf][(tid + l * 256) * 8]); \
    }                                                                          \
    _Pragma("unroll") for (int l = 0; l < BN / 32; ++l) {                      \
      int row = r0 + l * 32;                                                   \
      int sc = c0 ^ ((row & 7) * 8);                                           \
      GLDS16(Wb + (size_t)row * K + (k0) + sc, &Bs[buf][(tid + l * 256) * 8]); \
    }                                                                          \
  }

  int nt = Ks / BK;
  STAGE(0, 0)
  __syncthreads();
  for (int t = 0; t < nt; ++t) {
    int cur = t & 1;
    if (t + 1 < nt) STAGE(cur ^ 1, (t + 1) * BK)
#pragma unroll
    for (int kk = 0; kk < 2; ++kk) {
      bf16x8 af[MT], bfr[NT];
#pragma unroll
      for (int i = 0; i < MT; ++i) {
        int row = wr * (BM / 2) + i * 16 + cl;
        af[i] = *(const bf16x8*)&As[cur][row * BK + ((kk * 32 + grp * 8) ^ ((row & 7) * 8))];
      }
#pragma unroll
      for (int j = 0; j < NT; ++j) {
        int row = wc * (BN / 2) + j * 16 + cl;
        bfr[j] = *(const bf16x8*)&Bs[cur][row * BK + ((kk * 32 + grp * 8) ^ ((row & 7) * 8))];
      }
#pragma unroll
      for (int i = 0; i < MT; ++i)
#pragma unroll
        for (int j = 0; j < NT; ++j) acc[i][j] = MFMA16(af[i], bfr[j], acc[i][j]);
    }
    __syncthreads();
  }
#undef STAGE

#pragma unroll
  for (int i = 0; i < MT; ++i) {
    int row = bm * BM + wr * (BM / 2) + i * 16 + grp * 4;
#pragma unroll
    for (int j = 0; j < NT; ++j) {
      int col = bn * BN + wc * (BN / 2) + j * 16 + cl;
#pragma unroll
      for (int r = 0; r < 4; ++r)
        P[(size_t)(row + r) * N + col] = acc[i][j][r];
    }
  }
}

// ---------------- reduce 2 fp32 partials -> bf16 (single rounding) ----------------
__global__ __launch_bounds__(256) void reduce2(const float* __restrict__ P0,
                                               const float* __restrict__ P1,
                                               unsigned short* __restrict__ out, int n) {
  int i = (blockIdx.x * 256 + threadIdx.x) * 4;
  if (i >= n) return;
  float4 a = *(const float4*)(P0 + i);
  float4 b = *(const float4*)(P1 + i);
  u16x4 o = {f2bf(a.x + b.x), f2bf(a.y + b.y), f2bf(a.z + b.z), f2bf(a.w + b.w)};
  *(u16x4*)(out + i) = o;
}

// ---------------- Causal flash attention: swapped-QK^T 32x32 MFMA, NO-MAX softmax --
__global__ __launch_bounds__(256) void attn_mfma(const unsigned short* __restrict__ qf_,
                                                 const unsigned short* __restrict__ kf_,
                                                 const unsigned short* __restrict__ vf_,
                                                 unsigned short* __restrict__ out) {
  __shared__ float MS[2][33][64];
  int tid = threadIdx.x;
  int wid = tid >> 6;
  int lane = tid & 63;
  int ll = lane & 31;
  int hi = lane >> 5;
  int bid = blockIdx.x;
  int xcd = bid & 7;
  int idx = bid >> 3;
  int qt = 63 - (idx >> 2);
  int bh = xcd + 8 * (idx & 3);
  int b = bh >> 4, h = bh & 15;
  const unsigned short* qb = qf_ + (size_t)bh * BH_STRIDE;
  const unsigned short* kb = kf_ + (size_t)bh * BH_STRIDE;
  const unsigned short* vb = vf_ + (size_t)bh * BH_STRIDE;
  int q0 = qt * 32;
  int nt = qt + 1;
  int full = nt - 1;
  int fs = wid * full / 4;
  int fe = (wid + 1) * full / 4;

  bf16x8 qf[4];
#pragma unroll
  for (int es = 0; es < 4; ++es)
    qf[es] = *(const bf16x8*)(qb + (size_t)((qt * 4 + es) * 64 + lane) * 8);

  f32x16 accO[2] = {};
  f32x16 lacc = {};

  int t = fs;
  for (; t + 1 < fe; t += 2) {
    bf16x8 ka[4], kb2[4];
#pragma unroll
    for (int es = 0; es < 4; ++es) {
      ka[es] = *(const bf16x8*)(kb + (size_t)((t * 4 + es) * 64 + lane) * 8);
      kb2[es] = *(const bf16x8*)(kb + (size_t)(((t + 1) * 4 + es) * 64 + lane) * 8);
    }
    f32x16 cA = {}, cB = {};
    __builtin_amdgcn_s_setprio(1);
    cA = MFMA32(ka[0], qf[0], cA);
    cA = MFMA32(ka[1], qf[1], cA);
    cA = MFMA32(ka[2], qf[2], cA);
    cA = MFMA32(ka[3], qf[3], cA);
    cB = MFMA32(kb2[0], qf[0], cB);
    cB = MFMA32(kb2[1], qf[1], cB);
    cB = MFMA32(kb2[2], qf[2], cB);
    cB = MFMA32(kb2[3], qf[3], cB);
    __builtin_amdgcn_s_setprio(0);
    float pA[16], pB[16];
#pragma unroll
    for (int r = 0; r < 16; ++r) { pA[r] = exp2f(cA[r]); pB[r] = exp2f(cB[r]); }
#pragma unroll
    for (int r = 0; r < 16; ++r) lacc[r] += pA[r] + pB[r];
    bf16x8 va[4], vb2[4];
#pragma unroll
    for (int ix = 0; ix < 4; ++ix) {
      va[ix] = *(const bf16x8*)(vb + (size_t)((t * 4 + ix) * 64 + lane) * 8);
      vb2[ix] = *(const bf16x8*)(vb + (size_t)(((t + 1) * 4 + ix) * 64 + lane) * 8);
    }
    unsigned wA0 = cvtpk(pA[0], pA[1]), wA1 = cvtpk(pA[2], pA[3]);
    unsigned wA2 = cvtpk(pA[4], pA[5]), wA3 = cvtpk(pA[6], pA[7]);
    unsigned wA4 = cvtpk(pA[8], pA[9]), wA5 = cvtpk(pA[10], pA[11]);
    unsigned wA6 = cvtpk(pA[12], pA[13]), wA7 = cvtpk(pA[14], pA[15]);
    unsigned wB0 = cvtpk(pB[0], pB[1]), wB1 = cvtpk(pB[2], pB[3]);
    unsigned wB2 = cvtpk(pB[4], pB[5]), wB3 = cvtpk(pB[6], pB[7]);
    unsigned wB4 = cvtpk(pB[8], pB[9]), wB5 = cvtpk(pB[10], pB[11]);
    unsigned wB6 = cvtpk(pB[12], pB[13]), wB7 = cvtpk(pB[14], pB[15]);
    asm("v_permlane32_swap_b32 %0, %1" : "+v"(wA0), "+v"(wA2));
    asm("v_permlane32_swap_b32 %0, %1" : "+v"(wA1), "+v"(wA3));
    asm("v_permlane32_swap_b32 %0, %1" : "+v"(wA4), "+v"(wA6));
    asm("v_permlane32_swap_b32 %0, %1" : "+v"(wA5), "+v"(wA7));
    asm("v_permlane32_swap_b32 %0, %1" : "+v"(wB0), "+v"(wB2));
    asm("v_permlane32_swap_b32 %0, %1" : "+v"(wB1), "+v"(wB3));
    asm("v_permlane32_swap_b32 %0, %1" : "+v"(wB4), "+v"(wB6));
    asm("v_permlane32_swap_b32 %0, %1" : "+v"(wB5), "+v"(wB7));
    u32x4 pA0v = {wA0, wA1, wA2, wA3}, pA1v = {wA4, wA5, wA6, wA7};
    u32x4 pB0v = {wB0, wB1, wB2, wB3}, pB1v = {wB4, wB5, wB6, wB7};
    bf16x8 bA0 = __builtin_bit_cast(bf16x8, pA0v), bA1 = __builtin_bit_cast(bf16x8, pA1v);
    bf16x8 bB0 = __builtin_bit_cast(bf16x8, pB0v), bB1 = __builtin_bit_cast(bf16x8, pB1v);
    __builtin_amdgcn_s_setprio(1);
    accO[0] = MFMA32(va[0], bA0, accO[0]);
    accO[0] = MFMA32(va[1], bA1, accO[0]);
    accO[0] = MFMA32(vb2[0], bB0, accO[0]);
    accO[0] = MFMA32(vb2[1], bB1, accO[0]);
    accO[1] = MFMA32(va[2], bA0, accO[1]);
    accO[1] = MFMA32(va[3], bA1, accO[1]);
    accO[1] = MFMA32(vb2[2], bB0, accO[1]);
    accO[1] = MFMA32(vb2[3], bB1, accO[1]);
    __builtin_amdgcn_s_setprio(0);
  }

#define ATT_ONE(T, MASKED)                                                          \
  {                                                                                 \
    bf16x8 kf1[4];                                                                  \
    _Pragma("unroll") for (int es = 0; es < 4; ++es)                                \
      kf1[es] = *(const bf16x8*)(kb + (size_t)(((T) * 4 + es) * 64 + lane) * 8);    \
    f32x16 c = {};                                                                  \
    __builtin_amdgcn_s_setprio(1);                                                  \
    c = MFMA32(kf1[0], qf[0], c);                                                   \
    c = MFMA32(kf1[1], qf[1], c);                                                   \
    c = MFMA32(kf1[2], qf[2], c);                                                   \
    c = MFMA32(kf1[3], qf[3], c);                                                   \
    __builtin_amdgcn_s_setprio(0);                                                  \
    float p1[16];                                                                   \
    _Pragma("unroll") for (int r = 0; r < 16; ++r) {                                \
      if (MASKED) {                                                                 \
        int keyloc = (r & 3) + 8 * (r >> 2) + 4 * hi;                               \
        p1[r] = (keyloc > ll) ? 0.f : exp2f(c[r]);                                  \
      } else p1[r] = exp2f(c[r]);                                                   \
    }                                                                               \
    _Pragma("unroll") for (int r = 0; r < 16; ++r) lacc[r] += p1[r];                \
    bf16x8 vf1[4];                                                                  \
    _Pragma("unroll") for (int ix = 0; ix < 4; ++ix)                                \
      vf1[ix] = *(const bf16x8*)(vb + (size_t)(((T) * 4 + ix) * 64 + lane) * 8);    \
    unsigned w0 = cvtpk(p1[0], p1[1]), w1 = cvtpk(p1[2], p1[3]);                    \
    unsigned w2 = cvtpk(p1[4], p1[5]), w3 = cvtpk(p1[6], p1[7]);                    \
    unsigned w4 = cvtpk(p1[8], p1[9]), w5 = cvtpk(p1[10], p1[11]);                  \
    unsigned w6 = cvtpk(p1[12], p1[13]), w7 = cvtpk(p1[14], p1[15]);                \
    asm("v_permlane32_swap_b32 %0, %1" : "+v"(w0), "+v"(w2));                       \
    asm("v_permlane32_swap_b32 %0, %1" : "+v"(w1), "+v"(w3));                       \
    asm("v_permlane32_swap_b32 %0, %1" : "+v"(w4), "+v"(w6));                       \
    asm("v_permlane32_swap_b32 %0, %1" : "+v"(w5), "+v"(w7));                       \
    u32x4 pw0 = {w0, w1, w2, w3};                                                   \
    u32x4 pw1 = {w4, w5, w6, w7};                                                   \
    bf16x8 pb0 = __builtin_bit_cast(bf16x8, pw0);                                   \
    bf16x8 pb1 = __builtin_bit_cast(bf16x8, pw1);                                   \
    __builtin_amdgcn_s_setprio(1);                                                  \
    accO[0] = MFMA32(vf1[0], pb0, accO[0]);                                         \
    accO[0] = MFMA32(vf1[1], pb1, accO[0]);                                         \
    accO[1] = MFMA32(vf1[2], pb0, accO[1]);                                         \
    accO[1] = MFMA32(vf1[3], pb1, accO[1]);                                         \
    __builtin_amdgcn_s_setprio(0);                                                  \
  }

  if (t < fe) ATT_ONE(t, false)
  if (wid == 3) ATT_ONE(full, true)
#undef ATT_ONE

  float l;
  {
    float s8[8];
#pragma unroll
    for (int r = 0; r < 8; ++r) s8[r] = lacc[r] + lacc[r + 8];
    float s4a = s8[0] + s8[4], s4b = s8[1] + s8[5], s4c = s8[2] + s8[6], s4d = s8[3] + s8[7];
    l = (s4a + s4b) + (s4c + s4d);
  }

  auto publish = [&](int slot) {
#pragma unroll
    for (int r = 0; r < 16; ++r) {
      MS[slot][r][lane] = accO[0][r];
      MS[slot][16 + r][lane] = accO[1][r];
    }
    MS[slot][32][lane] = l;
  };
  auto merge = [&](int slot) {
    l += MS[slot][32][lane];
#pragma unroll
    for (int r = 0; r < 16; ++r) {
      accO[0][r] += MS[slot][r][lane];
      accO[1][r] += MS[slot][16 + r][lane];
    }
  };
  if (wid == 1) publish(0);
  if (wid == 3) publish(1);
  __syncthreads();
  if (wid == 0) merge(0);
  if (wid == 2) merge(1);
  __syncthreads();
  if (wid == 2) publish(0);
  __syncthreads();
  if (wid == 0) {
    merge(0);
    float ltot = l + __shfl_xor(l, 32, 64);
    float inv = 1.f / ltot;
    unsigned short* orow = out + (size_t)(b * Sc + q0 + ll) * Dc + h * Ec;
#pragma unroll
    for (int eo = 0; eo < 2; ++eo)
#pragma unroll
      for (int g = 0; g < 4; ++g) {
        u16x4 o4 = {f2bf(accO[eo][4 * g + 0] * inv), f2bf(accO[eo][4 * g + 1] * inv),
                    f2bf(accO[eo][4 * g + 2] * inv), f2bf(accO[eo][4 * g + 3] * inv)};
        *(u16x4*)(orow + eo * 32 + 8 * g + 4 * hi) = o4;
      }
  }
}

extern "C" void kernel_launch(void* const* d_in, const int* in_sizes, int n_in,
                              void* d_out, int out_size, void* d_ws, size_t ws_size,
                              hipStream_t stream) {
  const float* hidden = (const float*)d_in[0];
  const float* ln1_w = (const float*)d_in[1];
  const float* ln1_b = (const float*)d_in[2];
  const float* q_U = (const float*)d_in[3];
  const float* q_V = (const float*)d_in[4];
  const float* q_bias = (const float*)d_in[5];
  const float* k_U = (const float*)d_in[6];
  const float* k_V = (const float*)d_in[7];
  const float* k_bias = (const float*)d_in[8];
  const float* v_U = (const float*)d_in[9];
  const float* v_V = (const float*)d_in[10];
  const float* v_bias = (const float*)d_in[11];
  const float* out_U = (const float*)d_in[12];
  const float* out_V = (const float*)d_in[13];
  const float* out_bias = (const float*)d_in[14];
  const float* ln2_w = (const float*)d_in[15];
  const float* ln2_b = (const float*)d_in[16];
  const float* fc1_U = (const float*)d_in[17];
  const float* fc1_V = (const float*)d_in[18];
  const float* fc1_bias = (const float*)d_in[19];
  const float* fc2_U = (const float*)d_in[20];
  const float* fc2_V = (const float*)d_in[21];
  const float* fc2_bias = (const float*)d_in[22];
  float* out = (float*)d_out;
  float* ws = (float*)d_ws;
  unsigned short* wsu = (unsigned short*)d_ws;

  // ---- bf16 weight arena (ushort offsets) ----
  unsigned short* wOUTV = wsu + 1572864;    // [512,1024]
  unsigned short* wOUTU = wsu + 2097152;    // [1024,512]
  unsigned short* wFC1V = wsu + 2621440;    // [512,1024]
  unsigned short* wFC1U = wsu + 3145728;    // [4096,512]
  unsigned short* wFC2V = wsu + 5242880;    // [512,4096]
  unsigned short* wFC2U = wsu + 7340032;    // [1024,512]

  // ---- activation arena (float offsets) — identical to r21 (audited) ----
  float* h1 = ws + 4194304;
  unsigned short* Wqkv = (unsigned short*)(ws + 4194304);      // [3072,1024] bf16 (dead h1)
  float* qkv_biasF = ws + 6000000;                             // [3072] fp32 (dead h1)
  unsigned short* attn_out = (unsigned short*)(ws + 6291456);
  unsigned short* normed = (unsigned short*)(ws + 8388608);
  unsigned short* rbB = (unsigned short*)(ws + 10485760);
  unsigned short* ff = (unsigned short*)(ws + 11534336);
  unsigned short* qbuf = (unsigned short*)(ws + 16777216);
  unsigned short* kbuf = (unsigned short*)(ws + 18874368);
  unsigned short* vtbuf = (unsigned short*)(ws + 20971520);
  float* P0f = ws + 8388608;                                   // (dead normed)
  float* P1f = ws + 19922944;                                  // (dead vt region)
  unsigned short* rbG2 = (unsigned short*)(ws + 10485760);     // (dead rbB)

  const int M = Bc * Sc;  // 4096
  dim3 blk(256);

  // ---- W_qkv = U·V per head (+SCLOG2E fold on q) ----
  makew<<<768, blk, 0, stream>>>(q_U, k_U, v_U, q_V, k_V, v_V, Wqkv);
  // ---- weight conversion + LN1 + qkv-bias concat ----
  prep<<<6144 + M + 3, blk, 0, stream>>>(out_V, out_U, fc1_V, fc1_U, fc2_V, fc2_U,
                                         wsu, hidden, ln1_w, ln1_b, normed,
                                         q_bias, k_bias, v_bias, qkv_biasF);

  // ---- fused dense QKV projection, writes fragment-packed q/k/vt directly ----
  gemm_qkv<<<1536, blk, 0, stream>>>(normed, Wqkv, qkv_biasF, qbuf, kbuf, vtbuf, Dc, 32);

  // ---- causal attention -> attn_out (bf16) ----
  attn_mfma<<<2048, blk, 0, stream>>>(qbuf, kbuf, vtbuf, attn_out);

  // ---- output projection + residual -> h1 (fp32) ----
  gemm_bf16<64, 32><<<1024, blk, 0, stream>>>(attn_out, wOUTV, nullptr, rbB, nullptr, nullptr,
                                              M, 512, Dc, 0, 64);
  gemm_bf16<64, 64><<<1024, blk, 0, stream>>>(rbB, wOUTU, h1, nullptr, out_bias, hidden,
                                              M, Dc, 512, 0, 64);

  // ---- LN2 + FF ----
  ln_bf16<<<M, blk, 0, stream>>>(h1, ln2_w, ln2_b, normed);
  gemm_bf16<64, 32><<<1024, blk, 0, stream>>>(normed, wFC1V, nullptr, rbB, nullptr, nullptr,
                                              M, 512, Dc, 0, 64);
  gemm_bf16<128, 64><<<2048, blk, 0, stream>>>(rbB, wFC1U, nullptr, ff, fc1_bias, nullptr,
                                               M, DFFc, 512, 1, 32);
  // ---- fc2_V split-K x2 (fp32 partials, disjoint buffers, exact reduce) ----
  gemm_splitk2<64, 64><<<1024, blk, 0, stream>>>(ff, wFC2V, P0f, P1f, M, 512, DFFc, 64);
  reduce2<<<2048, blk, 0, stream>>>(P0f, P1f, rbG2, M * 512);
  gemm_bf16<64, 64><<<1024, blk, 0, stream>>>(rbG2, wFC2U, out, nullptr, fc2_bias, h1,
                                              M, Dc, 512, 0, 64);
}